// Round 6
// baseline (359.881 us; speedup 1.0000x reference)
//
#include <hip/hip_runtime.h>
#include <hip/hip_bf16.h>

// GNN forward: 3 layers of COO SpMM + gating, mean over layer embeddings.
// N=50000, E=800000, D=96.
//
// Round-6 = round-4 structure (best known: 213 us) + latency-attack on the
// gather loop:
//  - single flat ELL (PAD=64) keyed by dest row, int4 paired loads
//  - SpMM: 6 threads/row x 2 uint4 bf16 chunks, EIGHT-neighbor unroll
//    (16 gathers in flight), self/acc loads hoisted above the loop
//  - block=128 to reduce grid quantization tail (2344 blocks, 9.2/CU)
//  - last layer skips the dead ego_out store
//  - bf16 features (fp32 accum), X->bf16 fused into setup

#define N_NODES 50000
#define N_EDGES 800000
#define EMB 96
#define C16 12                    // 16B bf16 chunks per row (8 bf16 each)
#define TPR 6                     // threads per row (2 chunks each)
#define LAYER_NUM 3
#define PAD 64                    // ELL slots per row
#define NCHUNK (N_NODES * C16)    // 600000

__device__ __forceinline__ float bflo(unsigned u) { return __uint_as_float(u << 16); }
__device__ __forceinline__ float bfhi(unsigned u) { return __uint_as_float(u & 0xffff0000u); }

__device__ __forceinline__ void fma_bf8(float* s, float v, const uint4& u) {
    s[0] = fmaf(v, bflo(u.x), s[0]);
    s[1] = fmaf(v, bfhi(u.x), s[1]);
    s[2] = fmaf(v, bflo(u.y), s[2]);
    s[3] = fmaf(v, bfhi(u.y), s[3]);
    s[4] = fmaf(v, bflo(u.z), s[4]);
    s[5] = fmaf(v, bfhi(u.z), s[5]);
    s[6] = fmaf(v, bflo(u.w), s[6]);
    s[7] = fmaf(v, bfhi(u.w), s[7]);
}

// RNE pack: a -> low 16, b -> high 16
__device__ __forceinline__ unsigned packbf(float a, float b) {
    unsigned ua = __float_as_uint(a);
    unsigned ub = __float_as_uint(b);
    ua = (ua + 0x7fffu + ((ua >> 16) & 1u)) >> 16;
    ub = (ub + 0x7fffu + ((ub >> 16) & 1u)) & 0xffff0000u;
    return ua | ub;
}

// Fused: X(fp32) -> Xb(bf16) convert  +  edge binning into ELL.
__global__ void setup_kernel(const float4* __restrict__ X4,
                             uint4* __restrict__ Xb,
                             const int* __restrict__ rows,
                             const int* __restrict__ cols,
                             const float* __restrict__ vals,
                             int* __restrict__ cnt,
                             int2* __restrict__ ell) {
    int tid = blockIdx.x * blockDim.x + threadIdx.x;
    if (tid < NCHUNK) {
        float4 a = X4[tid * 2];
        float4 b = X4[tid * 2 + 1];
        uint4 o;
        o.x = packbf(a.x, a.y);
        o.y = packbf(a.z, a.w);
        o.z = packbf(b.x, b.y);
        o.w = packbf(b.z, b.w);
        Xb[tid] = o;
    }
    if (tid < N_EDGES) {
        int r = rows[tid];
        int slot = atomicAdd(&cnt[r], 1);
        if (slot < PAD) {
            int2 p;
            p.x = cols[tid];
            p.y = __float_as_int(vals[tid]);
            ell[r * PAD + slot] = p;
        }
    }
}

// One thread per (row, pair-of-16B-chunks): chunks ct and ct+TPR.
// FIRST: ego_in is Xb, acc is write-only (acc = X + ego1).
// LAST: skip ego_out store, fold /4 mean via scale.
template <bool FIRST, bool LAST>
__global__ void spmm_fused_kernel(const uint4* __restrict__ ego_in,
                                  uint4* __restrict__ ego_out,
                                  const int* __restrict__ cnt,
                                  const int4* __restrict__ ell4,
                                  float4* __restrict__ acc,
                                  float scale) {
    int tid = blockIdx.x * blockDim.x + threadIdx.x;
    if (tid >= N_NODES * TPR) return;
    int row = tid / TPR;
    int ct  = tid % TPR;

    int deg = cnt[row];
    if (deg > PAD) deg = PAD;
    const int4* ep = ell4 + row * (PAD / 2);

    // hoist self-row + acc loads: independent of the gather chain
    int ib = row * C16 + ct;
    uint4 ea = ego_in[ib];
    uint4 eb = ego_in[ib + TPR];
    int ia = row * (EMB / 4) + ct * 2;
    float4 a0, a1, a2, a3;
    if (!FIRST) {
        a0 = acc[ia];
        a1 = acc[ia + 1];
        a2 = acc[ia + 12];
        a3 = acc[ia + 13];
    }

    float s0[8] = {0.f, 0.f, 0.f, 0.f, 0.f, 0.f, 0.f, 0.f};
    float s1[8] = {0.f, 0.f, 0.f, 0.f, 0.f, 0.f, 0.f, 0.f};

    int j = 0;
    for (; j + 8 <= deg; j += 8) {
        int4 pA = ep[(j >> 1) + 0];
        int4 pB = ep[(j >> 1) + 1];
        int4 pC = ep[(j >> 1) + 2];
        int4 pD = ep[(j >> 1) + 3];
        const uint4* b0 = ego_in + pA.x * C16;
        const uint4* b1 = ego_in + pA.z * C16;
        const uint4* b2 = ego_in + pB.x * C16;
        const uint4* b3 = ego_in + pB.z * C16;
        const uint4* b4 = ego_in + pC.x * C16;
        const uint4* b5 = ego_in + pC.z * C16;
        const uint4* b6 = ego_in + pD.x * C16;
        const uint4* b7 = ego_in + pD.z * C16;
        uint4 x0a = b0[ct], x0b = b0[ct + TPR];
        uint4 x1a = b1[ct], x1b = b1[ct + TPR];
        uint4 x2a = b2[ct], x2b = b2[ct + TPR];
        uint4 x3a = b3[ct], x3b = b3[ct + TPR];
        uint4 x4a = b4[ct], x4b = b4[ct + TPR];
        uint4 x5a = b5[ct], x5b = b5[ct + TPR];
        uint4 x6a = b6[ct], x6b = b6[ct + TPR];
        uint4 x7a = b7[ct], x7b = b7[ct + TPR];
        float v0 = __int_as_float(pA.y), v1 = __int_as_float(pA.w);
        float v2 = __int_as_float(pB.y), v3 = __int_as_float(pB.w);
        float v4 = __int_as_float(pC.y), v5 = __int_as_float(pC.w);
        float v6 = __int_as_float(pD.y), v7 = __int_as_float(pD.w);
        fma_bf8(s0, v0, x0a); fma_bf8(s1, v0, x0b);
        fma_bf8(s0, v1, x1a); fma_bf8(s1, v1, x1b);
        fma_bf8(s0, v2, x2a); fma_bf8(s1, v2, x2b);
        fma_bf8(s0, v3, x3a); fma_bf8(s1, v3, x3b);
        fma_bf8(s0, v4, x4a); fma_bf8(s1, v4, x4b);
        fma_bf8(s0, v5, x5a); fma_bf8(s1, v5, x5b);
        fma_bf8(s0, v6, x6a); fma_bf8(s1, v6, x6b);
        fma_bf8(s0, v7, x7a); fma_bf8(s1, v7, x7b);
    }
    for (; j + 2 <= deg; j += 2) {
        int4 pA = ep[j >> 1];
        const uint4* b0 = ego_in + pA.x * C16;
        const uint4* b1 = ego_in + pA.z * C16;
        uint4 x0a = b0[ct], x0b = b0[ct + TPR];
        uint4 x1a = b1[ct], x1b = b1[ct + TPR];
        float v0 = __int_as_float(pA.y);
        float v1 = __int_as_float(pA.w);
        fma_bf8(s0, v0, x0a); fma_bf8(s1, v0, x0b);
        fma_bf8(s0, v1, x1a); fma_bf8(s1, v1, x1b);
    }
    if (j < deg) {
        int2 p = ((const int2*)ell4)[row * PAD + j];
        const uint4* b0 = ego_in + p.x * C16;
        uint4 x0a = b0[ct], x0b = b0[ct + TPR];
        float v0 = __int_as_float(p.y);
        fma_bf8(s0, v0, x0a); fma_bf8(s1, v0, x0b);
    }

    float e0[8] = {bflo(ea.x), bfhi(ea.x), bflo(ea.y), bfhi(ea.y),
                   bflo(ea.z), bfhi(ea.z), bflo(ea.w), bfhi(ea.w)};
    float e1[8] = {bflo(eb.x), bfhi(eb.x), bflo(eb.y), bfhi(eb.y),
                   bflo(eb.z), bfhi(eb.z), bflo(eb.w), bfhi(eb.w)};
    float n0[8], n1[8];
#pragma unroll
    for (int k = 0; k < 8; ++k) {
        n0[k] = fmaf(s0[k], e0[k], s0[k]);   // s*(1+e)
        n1[k] = fmaf(s1[k], e1[k], s1[k]);
    }

    if (!LAST) {
        uint4 oa, ob;
        oa.x = packbf(n0[0], n0[1]); oa.y = packbf(n0[2], n0[3]);
        oa.z = packbf(n0[4], n0[5]); oa.w = packbf(n0[6], n0[7]);
        ob.x = packbf(n1[0], n1[1]); ob.y = packbf(n1[2], n1[3]);
        ob.z = packbf(n1[4], n1[5]); ob.w = packbf(n1[6], n1[7]);
        ego_out[ib]       = oa;
        ego_out[ib + TPR] = ob;
    }

    if (FIRST) {
        a0 = make_float4(e0[0] + n0[0], e0[1] + n0[1], e0[2] + n0[2], e0[3] + n0[3]);
        a1 = make_float4(e0[4] + n0[4], e0[5] + n0[5], e0[6] + n0[6], e0[7] + n0[7]);
        a2 = make_float4(e1[0] + n1[0], e1[1] + n1[1], e1[2] + n1[2], e1[3] + n1[3]);
        a3 = make_float4(e1[4] + n1[4], e1[5] + n1[5], e1[6] + n1[6], e1[7] + n1[7]);
    } else {
        a0.x = (a0.x + n0[0]) * scale; a0.y = (a0.y + n0[1]) * scale;
        a0.z = (a0.z + n0[2]) * scale; a0.w = (a0.w + n0[3]) * scale;
        a1.x = (a1.x + n0[4]) * scale; a1.y = (a1.y + n0[5]) * scale;
        a1.z = (a1.z + n0[6]) * scale; a1.w = (a1.w + n0[7]) * scale;
        a2.x = (a2.x + n1[0]) * scale; a2.y = (a2.y + n1[1]) * scale;
        a2.z = (a2.z + n1[2]) * scale; a2.w = (a2.w + n1[3]) * scale;
        a3.x = (a3.x + n1[4]) * scale; a3.y = (a3.y + n1[5]) * scale;
        a3.z = (a3.z + n1[6]) * scale; a3.w = (a3.w + n1[7]) * scale;
    }
    acc[ia]      = a0;
    acc[ia + 1]  = a1;
    acc[ia + 12] = a2;
    acc[ia + 13] = a3;
}

extern "C" void kernel_launch(void* const* d_in, const int* in_sizes, int n_in,
                              void* d_out, int out_size, void* d_ws, size_t ws_size,
                              hipStream_t stream) {
    const float* X    = (const float*)d_in[0];
    const float* vals = (const float*)d_in[1];
    const int*   rows = (const int*)d_in[2];
    const int*   cols = (const int*)d_in[3];

    const size_t nodeb_bytes = (size_t)NCHUNK * sizeof(uint4);       // 9.6 MB
    const size_t ell_bytes   = (size_t)N_NODES * PAD * sizeof(int2); // 25.6 MB
    const size_t cnt_bytes   = (size_t)N_NODES * sizeof(int);

    float* acc = (float*)d_out;

    char* w = (char*)d_ws;
    uint4* Xb    = (uint4*)w;  w += nodeb_bytes;
    uint4* ego_a = (uint4*)w;  w += nodeb_bytes;
    uint4* ego_b = (uint4*)w;  w += nodeb_bytes;
    int2*  ell   = (int2*)w;   w += ell_bytes;
    int*   cnt   = (int*)w;

    hipMemsetAsync(cnt, 0, cnt_bytes, stream);
    setup_kernel<<<(N_EDGES + 255) / 256, 256, 0, stream>>>(
        (const float4*)X, Xb, rows, cols, vals, cnt, ell);

    const int blocks = (N_NODES * TPR + 127) / 128;
    const float last_scale = 1.0f / (LAYER_NUM + 1);

    spmm_fused_kernel<true, false><<<blocks, 128, 0, stream>>>(
        Xb, ego_a, cnt, (const int4*)ell, (float4*)acc, 1.0f);
    spmm_fused_kernel<false, false><<<blocks, 128, 0, stream>>>(
        ego_a, ego_b, cnt, (const int4*)ell, (float4*)acc, 1.0f);
    spmm_fused_kernel<false, true><<<blocks, 128, 0, stream>>>(
        ego_b, ego_a, cnt, (const int4*)ell, (float4*)acc, last_scale);
}

// Round 7
// 216.907 us; speedup vs baseline: 1.6591x; 1.6591x over previous
//
#include <hip/hip_runtime.h>
#include <hip/hip_bf16.h>

// GNN forward: 3 layers of COO SpMM + gating, mean over layer embeddings.
// N=50000, E=800000, D=96.
//
// Round-7 = round-4 structure with the SpMM thread mapping fixed:
//  - 12 threads/row, 1 uint4 bf16 chunk each -> every store instruction is
//    lane-contiguous (r6's 6-thr/row mapping caused 4x write amplification:
//    WRITE_SIZE 123 MB vs 29 logical).
//  - flat ELL (PAD=64, 8B entries), 4-neighbor unroll via paired int4 loads,
//    self-row + acc loads hoisted above the gather loop.
//  - last layer skips the dead ego_out store.
//  - bf16 features (fp32 accum), X->bf16 fused into setup (r4-identical).

#define N_NODES 50000
#define N_EDGES 800000
#define EMB 96
#define C16 12                    // 16B bf16 chunks per row
#define LAYER_NUM 3
#define PAD 64                    // ELL slots per row
#define NCHUNK (N_NODES * C16)    // 600000

__device__ __forceinline__ float bflo(unsigned u) { return __uint_as_float(u << 16); }
__device__ __forceinline__ float bfhi(unsigned u) { return __uint_as_float(u & 0xffff0000u); }

__device__ __forceinline__ void fma_bf8(float* s, float v, const uint4& u) {
    s[0] = fmaf(v, bflo(u.x), s[0]);
    s[1] = fmaf(v, bfhi(u.x), s[1]);
    s[2] = fmaf(v, bflo(u.y), s[2]);
    s[3] = fmaf(v, bfhi(u.y), s[3]);
    s[4] = fmaf(v, bflo(u.z), s[4]);
    s[5] = fmaf(v, bfhi(u.z), s[5]);
    s[6] = fmaf(v, bflo(u.w), s[6]);
    s[7] = fmaf(v, bfhi(u.w), s[7]);
}

// RNE pack: a -> low 16, b -> high 16
__device__ __forceinline__ unsigned packbf(float a, float b) {
    unsigned ua = __float_as_uint(a);
    unsigned ub = __float_as_uint(b);
    ua = (ua + 0x7fffu + ((ua >> 16) & 1u)) >> 16;
    ub = (ub + 0x7fffu + ((ub >> 16) & 1u)) & 0xffff0000u;
    return ua | ub;
}

// Fused: X(fp32) -> Xb(bf16) convert  +  edge binning into ELL. (r4-identical)
__global__ void setup_kernel(const float4* __restrict__ X4,
                             uint4* __restrict__ Xb,
                             const int* __restrict__ rows,
                             const int* __restrict__ cols,
                             const float* __restrict__ vals,
                             int* __restrict__ cnt,
                             int2* __restrict__ ell) {
    int tid = blockIdx.x * blockDim.x + threadIdx.x;
    if (tid < NCHUNK) {
        float4 a = X4[tid * 2];
        float4 b = X4[tid * 2 + 1];
        uint4 o;
        o.x = packbf(a.x, a.y);
        o.y = packbf(a.z, a.w);
        o.z = packbf(b.x, b.y);
        o.w = packbf(b.z, b.w);
        Xb[tid] = o;
    }
    if (tid < N_EDGES) {
        int r = rows[tid];
        int slot = atomicAdd(&cnt[r], 1);
        if (slot < PAD) {
            int2 p;
            p.x = cols[tid];
            p.y = __float_as_int(vals[tid]);
            ell[r * PAD + slot] = p;
        }
    }
}

// One thread per (row, 16B chunk): 12 threads/row.
// FIRST: ego_in is Xb, acc is write-only (acc = X + ego1).
// LAST: skip ego_out store, fold /4 mean via scale.
template <bool FIRST, bool LAST>
__global__ void spmm_fused_kernel(const uint4* __restrict__ ego_in,
                                  uint4* __restrict__ ego_out,
                                  const int* __restrict__ cnt,
                                  const int4* __restrict__ ell4,
                                  float4* __restrict__ acc,
                                  float scale) {
    int tid = blockIdx.x * blockDim.x + threadIdx.x;
    if (tid >= N_NODES * C16) return;
    int row = tid / C16;
    int ct  = tid % C16;

    int deg = cnt[row];
    if (deg > PAD) deg = PAD;
    const int4* ep = ell4 + row * (PAD / 2);

    // hoisted: independent of the gather chain
    int ib = row * C16 + ct;
    uint4 ea = ego_in[ib];
    int ia = row * (EMB / 4) + ct * 2;
    float4 a0, a1;
    if (!FIRST) {
        a0 = acc[ia];
        a1 = acc[ia + 1];
    }

    float s[8] = {0.f, 0.f, 0.f, 0.f, 0.f, 0.f, 0.f, 0.f};

    int j = 0;
    for (; j + 4 <= deg; j += 4) {
        int4 pA = ep[(j >> 1) + 0];
        int4 pB = ep[(j >> 1) + 1];
        uint4 x0 = ego_in[pA.x * C16 + ct];
        uint4 x1 = ego_in[pA.z * C16 + ct];
        uint4 x2 = ego_in[pB.x * C16 + ct];
        uint4 x3 = ego_in[pB.z * C16 + ct];
        fma_bf8(s, __int_as_float(pA.y), x0);
        fma_bf8(s, __int_as_float(pA.w), x1);
        fma_bf8(s, __int_as_float(pB.y), x2);
        fma_bf8(s, __int_as_float(pB.w), x3);
    }
    if (j + 2 <= deg) {
        int4 pA = ep[j >> 1];
        uint4 x0 = ego_in[pA.x * C16 + ct];
        uint4 x1 = ego_in[pA.z * C16 + ct];
        fma_bf8(s, __int_as_float(pA.y), x0);
        fma_bf8(s, __int_as_float(pA.w), x1);
        j += 2;
    }
    if (j < deg) {
        int2 p = ((const int2*)ell4)[row * PAD + j];
        uint4 x0 = ego_in[p.x * C16 + ct];
        fma_bf8(s, __int_as_float(p.y), x0);
    }

    float e0[8] = {bflo(ea.x), bfhi(ea.x), bflo(ea.y), bfhi(ea.y),
                   bflo(ea.z), bfhi(ea.z), bflo(ea.w), bfhi(ea.w)};
    float n0[8];
#pragma unroll
    for (int k = 0; k < 8; ++k) n0[k] = fmaf(s[k], e0[k], s[k]);   // s*(1+e)

    if (!LAST) {
        uint4 oa;
        oa.x = packbf(n0[0], n0[1]); oa.y = packbf(n0[2], n0[3]);
        oa.z = packbf(n0[4], n0[5]); oa.w = packbf(n0[6], n0[7]);
        ego_out[ib] = oa;
    }

    if (FIRST) {
        a0 = make_float4(e0[0] + n0[0], e0[1] + n0[1], e0[2] + n0[2], e0[3] + n0[3]);
        a1 = make_float4(e0[4] + n0[4], e0[5] + n0[5], e0[6] + n0[6], e0[7] + n0[7]);
    } else {
        a0.x = (a0.x + n0[0]) * scale; a0.y = (a0.y + n0[1]) * scale;
        a0.z = (a0.z + n0[2]) * scale; a0.w = (a0.w + n0[3]) * scale;
        a1.x = (a1.x + n0[4]) * scale; a1.y = (a1.y + n0[5]) * scale;
        a1.z = (a1.z + n0[6]) * scale; a1.w = (a1.w + n0[7]) * scale;
    }
    acc[ia]     = a0;
    acc[ia + 1] = a1;
}

extern "C" void kernel_launch(void* const* d_in, const int* in_sizes, int n_in,
                              void* d_out, int out_size, void* d_ws, size_t ws_size,
                              hipStream_t stream) {
    const float* X    = (const float*)d_in[0];
    const float* vals = (const float*)d_in[1];
    const int*   rows = (const int*)d_in[2];
    const int*   cols = (const int*)d_in[3];

    const size_t nodeb_bytes = (size_t)NCHUNK * sizeof(uint4);       // 9.6 MB
    const size_t ell_bytes   = (size_t)N_NODES * PAD * sizeof(int2); // 25.6 MB
    const size_t cnt_bytes   = (size_t)N_NODES * sizeof(int);

    float* acc = (float*)d_out;

    char* w = (char*)d_ws;
    uint4* Xb    = (uint4*)w;  w += nodeb_bytes;
    uint4* ego_a = (uint4*)w;  w += nodeb_bytes;
    uint4* ego_b = (uint4*)w;  w += nodeb_bytes;
    int2*  ell   = (int2*)w;   w += ell_bytes;
    int*   cnt   = (int*)w;

    hipMemsetAsync(cnt, 0, cnt_bytes, stream);
    setup_kernel<<<(N_EDGES + 255) / 256, 256, 0, stream>>>(
        (const float4*)X, Xb, rows, cols, vals, cnt, ell);

    const int blocks = (N_NODES * C16 + 255) / 256;
    const float last_scale = 1.0f / (LAYER_NUM + 1);

    spmm_fused_kernel<true, false><<<blocks, 256, 0, stream>>>(
        Xb, ego_a, cnt, (const int4*)ell, (float4*)acc, 1.0f);
    spmm_fused_kernel<false, false><<<blocks, 256, 0, stream>>>(
        ego_a, ego_b, cnt, (const int4*)ell, (float4*)acc, 1.0f);
    spmm_fused_kernel<false, true><<<blocks, 256, 0, stream>>>(
        ego_b, ego_a, cnt, (const int4*)ell, (float4*)acc, last_scale);
}